// Round 1
// baseline (199.072 us; speedup 1.0000x reference)
//
#include <hip/hip_runtime.h>
#include <hip/hip_bf16.h>

// Problem: B=256, A=128, F=512, D=6, C=512
// out[b,a,:] = (atoms[b,a,:] + sum_j atoms[b,bonds[b,a,j],:]) @ W[deg] + bias[deg]
// deg = count(bonds != -1), in 0..5.
//
// R5: (1) gemm 2-phase prefetch — double-buffered LDS, stage K-tile k+1 via
//     global_load_lds while MFMAs chew tile k; ONE barrier per K-step.
//     (2) gemm grid: bijective XCD-clustered decode so the 4 n-tiles of one
//     (d,m0) row-tile run back-to-back on the same XCD (A-rows hit L2).
//     (3) sum_neigh: XCD-chunked block swizzle — each XCD owns contiguous
//     molecules, neighbor gather hits its own L2 instead of L3.
//     (4) counts zeroing folded into transpose_w (memset dispatch dropped).

#define NB 256
#define NA 128
#define NF 512
#define ND 6
#define NC 512
#define NATOMS (NB * NA)   // 32768

typedef __attribute__((ext_vector_type(8))) short frag8;
typedef __attribute__((ext_vector_type(4))) float f32x4;

static __device__ inline unsigned short f2bu(float f) {
    __hip_bfloat16 h = __float2bfloat16(f);
    return *reinterpret_cast<unsigned short*>(&h);
}
static __device__ inline unsigned int pack2(float a, float b) {
    return (unsigned int)f2bu(a) | ((unsigned int)f2bu(b) << 16);
}
static __device__ inline void async16(const void* g, void* l) {
    __builtin_amdgcn_global_load_lds(
        (const __attribute__((address_space(1))) void*)g,
        (__attribute__((address_space(3))) void*)l, 16, 0, 0);
}

// ---------------- kernel T: W[d][f][c] (f32) -> Wt[d][c][f] (bf16) ----------------
// Also zeroes counts[] (runs before bucket_atoms on the stream).
__global__ void transpose_w(const float* __restrict__ W,
                            __hip_bfloat16* __restrict__ Wt,
                            int* __restrict__ counts) {
    if (blockIdx.x == 0 && blockIdx.y == 0 && blockIdx.z == 0 &&
        threadIdx.y == 0 && threadIdx.x < ND)
        counts[threadIdx.x] = 0;
    __shared__ float t[32][33];
    const int d  = blockIdx.z;
    const int c0 = blockIdx.x * 32;
    const int f0 = blockIdx.y * 32;
    #pragma unroll
    for (int r = 0; r < 32; r += 8)
        t[threadIdx.y + r][threadIdx.x] =
            W[((size_t)(d * NF + f0 + threadIdx.y + r)) * NC + c0 + threadIdx.x];
    __syncthreads();
    #pragma unroll
    for (int r = 0; r < 32; r += 8)
        Wt[((size_t)(d * NC + c0 + threadIdx.y + r)) * NF + f0 + threadIdx.x] =
            __float2bfloat16(t[threadIdx.x][threadIdx.y + r]);
}

// ---------------- kernel D: degree bucketing, LDS-aggregated ----------------
__global__ __launch_bounds__(256) void bucket_atoms(
    const int* __restrict__ bonds, int* __restrict__ counts,
    int* __restrict__ bucket) {
    __shared__ int lcnt[ND];
    __shared__ int lbase[ND];
    const int tid = threadIdx.x;
    if (tid < ND) lcnt[tid] = 0;
    __syncthreads();
    int deg[4], loc[4], gg[4];
    #pragma unroll
    for (int i = 0; i < 4; ++i) {
        int g = blockIdx.x * 1024 + i * 256 + tid;
        gg[i] = g;
        int dg = 0;
        #pragma unroll
        for (int j = 0; j < ND; ++j) dg += (bonds[g * ND + j] >= 0);
        deg[i] = dg;
        loc[i] = atomicAdd(&lcnt[dg], 1);      // LDS atomic — cheap
    }
    __syncthreads();
    if (tid < ND) lbase[tid] = atomicAdd(&counts[tid], lcnt[tid]);  // 6 global/block
    __syncthreads();
    #pragma unroll
    for (int i = 0; i < 4; ++i)
        bucket[deg[i] * NATOMS + lbase[deg[i]] + loc[i]] = gg[i];
}

// ---------------- kernel A: neighbor gather/sum (f32) -> summed (bf16) ----------
// XCD-chunked swizzle: blocks b with b%8==x map to chunk x*1024 + b/8, so each
// XCD processes 32 contiguous molecules — the 7x per-molecule gather re-reads
// hit that XCD's own L2 (4 MB >> 256 KB molecule) instead of bouncing to L3.
__global__ __launch_bounds__(256) void sum_neigh(
    const float* __restrict__ atoms, const int* __restrict__ bonds,
    __hip_bfloat16* __restrict__ summed) {
    const int tid  = threadIdx.x;
    const int wave = tid >> 6;
    const int lane = tid & 63;
    const int swz  = (blockIdx.x & 7) * (NATOMS / 4 / 8) + (blockIdx.x >> 3);
    const int g    = swz * 4 + wave;          // atom index [0, 32768)
    const float4* a4 = (const float4*)atoms;  // row = 128 float4

    int   nb[ND];
    float msk[ND];
    #pragma unroll
    for (int j = 0; j < ND; ++j) {
        int n = bonds[g * ND + j];
        msk[j] = (n >= 0) ? 1.0f : 0.0f;
        nb[j]  = (n >= 0) ? n : 0;            // dummy row 0, masked out
    }
    const int rowbase = g & ~(NA - 1);        // (g / NA) * NA

    float4 s0 = a4[(size_t)g * 128 + lane];
    float4 s1 = a4[(size_t)g * 128 + 64 + lane];
    float4 v0[ND], v1[ND];
    #pragma unroll
    for (int j = 0; j < ND; ++j) {
        const size_t base = (size_t)(rowbase + nb[j]) * 128;
        v0[j] = a4[base + lane];
        v1[j] = a4[base + 64 + lane];
    }
    #pragma unroll
    for (int j = 0; j < ND; ++j) {
        s0.x = fmaf(v0[j].x, msk[j], s0.x); s0.y = fmaf(v0[j].y, msk[j], s0.y);
        s0.z = fmaf(v0[j].z, msk[j], s0.z); s0.w = fmaf(v0[j].w, msk[j], s0.w);
        s1.x = fmaf(v1[j].x, msk[j], s1.x); s1.y = fmaf(v1[j].y, msk[j], s1.y);
        s1.z = fmaf(v1[j].z, msk[j], s1.z); s1.w = fmaf(v1[j].w, msk[j], s1.w);
    }

    uint2 o0, o1;
    o0.x = pack2(s0.x, s0.y); o0.y = pack2(s0.z, s0.w);
    o1.x = pack2(s1.x, s1.y); o1.y = pack2(s1.z, s1.w);
    ((uint2*)summed)[(size_t)g * 128 + lane] = o0;
    ((uint2*)summed)[(size_t)g * 128 + 64 + lane] = o1;
}

// ---------------- kernel B: per-degree gathered GEMM ----------------
// Tiles: BM=128, BN=128, BK=64. MFMA 16x16x32 bf16; 4 waves, each owns 64x64.
// 2-phase pipeline: double-buffered LDS; per K-step {stage(next via
// global_load_lds) ; ds_read+MFMA(cur) ; ONE __syncthreads (drains vmcnt)}.
// Grid decode: L = bx + 24*by; XCD x = L&7 owns (d,m0) pairs p ≡ x (mod 8);
// the 4 n-tiles of a pair are consecutive on that XCD → A-rows L2-resident.
__global__ __launch_bounds__(256, 2) void gemm_deg(
    const __hip_bfloat16* __restrict__ summed, const __hip_bfloat16* __restrict__ Wt,
    const float* __restrict__ bias, const int* __restrict__ counts,
    const int* __restrict__ bucket, float* __restrict__ out) {
    const int L  = blockIdx.x + 24 * blockIdx.y;   // 0..6143
    const int q  = L >> 3;                          // 0..767 (per-XCD seq)
    const int p  = ((q >> 2) << 3) + (L & 7);       // 0..1535: (d,m0) pair, p%8 = XCD
    const int d  = p % ND;
    const int m0 = (p / ND) * 128;
    const int n0 = (q & 3) * 128;                   // 4 n-tiles consecutive per pair
    const int Md = counts[d];
    if (m0 >= Md) return;

    __shared__ __align__(16) __hip_bfloat16 sA[2][128 * 64];  // [row][k]
    __shared__ __align__(16) __hip_bfloat16 sB[2][128 * 64];  // [n][k]  (Wt rows)
    __shared__ int sRows[128];

    const int tid = threadIdx.x;
    if (tid < 128) {
        int r = m0 + tid;
        sRows[tid] = (r < Md) ? bucket[d * NATOMS + r] : -1;
    }
    __syncthreads();

    const int lane = tid & 63;
    const int w    = tid >> 6;
    const int srow = lane >> 3;     // 0..7 within an 8-row chunk
    const int seg  = lane & 7;      // 16B segment within a 64-elem row

    // per-wave staging: wave w stages rows w*32 + c*8 + srow, c = 0..3
    const char* smB = (const char*)summed;
    const char* wtB = (const char*)Wt + (size_t)(d * NC + n0) * (NF * 2);
    size_t gA[4];
    int    rowc[4];
    #pragma unroll
    for (int c = 0; c < 4; ++c) {
        rowc[c] = w * 32 + c * 8 + srow;
        int qr = sRows[rowc[c]];
        gA[c] = (size_t)((qr < 0) ? 0 : qr) * (NF * 2);   // dummy row 0 (never stored)
    }

    const int quad = lane >> 4, l16 = lane & 15;
    const int wy = w >> 1, wx = w & 1;

    f32x4 acc[4][4];
    #pragma unroll
    for (int i = 0; i < 4; ++i)
        #pragma unroll
        for (int j = 0; j < 4; ++j) acc[i][j] = (f32x4)0.0f;

    auto stage = [&](int buf, int kt) {
        const int koff = kt * 128 + seg * 16;   // byte offset within a 1024B row
        #pragma unroll
        for (int c = 0; c < 4; ++c) {
            async16(smB + gA[c] + koff, &sA[buf][(w * 32 + c * 8) * 64]);
            async16(wtB + (size_t)rowc[c] * (NF * 2) + koff, &sB[buf][(w * 32 + c * 8) * 64]);
        }
    };
    auto compute = [&](int buf) {
        #pragma unroll
        for (int ks = 0; ks < 64; ks += 32) {
            frag8 aF[4], bF[4];
            #pragma unroll
            for (int i = 0; i < 4; ++i)
                aF[i] = *(const frag8*)&sA[buf][(wy * 64 + i * 16 + l16) * 64 + ks + quad * 8];
            #pragma unroll
            for (int j = 0; j < 4; ++j)
                bF[j] = *(const frag8*)&sB[buf][(wx * 64 + j * 16 + l16) * 64 + ks + quad * 8];
            #pragma unroll
            for (int i = 0; i < 4; ++i)
                #pragma unroll
                for (int j = 0; j < 4; ++j)
                    acc[i][j] = __builtin_amdgcn_mfma_f32_16x16x32_bf16(
                        aF[i], bF[j], acc[i][j], 0, 0, 0);
        }
    };

    // prologue: stage tile 0, drain, then 2-phase main loop
    stage(0, 0);
    __syncthreads();                 // compiler emits vmcnt(0) drain + barrier
    int cur = 0;
    #pragma unroll
    for (int kt = 1; kt < NF / 64; ++kt) {
        stage(cur ^ 1, kt);          // DMA next tile — in flight during MFMAs
        compute(cur);
        __syncthreads();             // drains vmcnt(0): next buffer ready
        cur ^= 1;
    }
    compute(cur);                    // last tile, no prefetch

    // epilogue: C/D layout col = lane&15, row = quad*4 + reg; output is FLOAT32
    #pragma unroll
    for (int j = 0; j < 4; ++j) {
        const int n = n0 + wx * 64 + j * 16 + l16;
        const float bv = bias[d * NC + n];
        #pragma unroll
        for (int i = 0; i < 4; ++i) {
            #pragma unroll
            for (int r = 0; r < 4; ++r) {
                const int tr = wy * 64 + i * 16 + quad * 4 + r;
                const int g  = sRows[tr];
                if (g >= 0)
                    out[(size_t)g * NC + n] = acc[i][j][r] + bv;
            }
        }
    }
}

extern "C" void kernel_launch(void* const* d_in, const int* in_sizes, int n_in,
                              void* d_out, int out_size, void* d_ws, size_t ws_size,
                              hipStream_t stream) {
    const float* atoms = (const float*)d_in[0];
    const int*   bonds = (const int*)d_in[1];
    const float* W     = (const float*)d_in[2];
    const float* bias  = (const float*)d_in[3];
    float* out = (float*)d_out;

    // workspace layout
    char* ws = (char*)d_ws;
    int* counts = (int*)ws;                                   // 6 ints
    int* bucket = (int*)(ws + 1024);                          // 6*32768 ints = 786432 B
    __hip_bfloat16* Wt     = (__hip_bfloat16*)(ws + 1024 + 786432);            // 3 MB
    __hip_bfloat16* summed = (__hip_bfloat16*)(ws + 1024 + 786432 + 3145728);  // 32 MB

    transpose_w<<<dim3(NC / 32, NF / 32, ND), dim3(32, 8), 0, stream>>>(W, Wt, counts);

    bucket_atoms<<<NATOMS / 1024, 256, 0, stream>>>(bonds, counts, bucket);

    sum_neigh<<<NATOMS / 4, 256, 0, stream>>>(atoms, bonds, summed);

    gemm_deg<<<dim3(24, NATOMS / 128), 256, 0, stream>>>(
        summed, Wt, bias, counts, bucket, out);
}

// Round 2
// 191.907 us; speedup vs baseline: 1.0373x; 1.0373x over previous
//
#include <hip/hip_runtime.h>
#include <hip/hip_bf16.h>

// Problem: B=256, A=128, F=512, D=6, C=512
// out[b,a,:] = (atoms[b,a,:] + sum_j atoms[b,bonds[b,a,j],:]) @ W[deg] + bias[deg]
// deg = count(bonds != -1), in 0..5.
//
// R6: gemm pipeline rebuilt as COUNTED-vmcnt 2-deep (T3/T4): raw s_barrier +
//     asm s_waitcnt vmcnt(8) — previous tile's 8 loads, never drain-0 in the
//     main loop, so the next tile's DMA stays in flight across the barrier.
//     + LDS XOR-swizzle (T2, rule 21: linear gload_lds dest, pre-swizzled
//     GLOBAL source seg^row&7, swizzled ds_read) to kill the 16-way conflict.
//     + s_setprio around MFMA cluster (T5).
//     Kept from R5: XCD-clustered grid decode (FETCH 68->29.5 MB, verified),
//     sum_neigh XCD chunking, counts zeroing folded into transpose_w.

#define NB 256
#define NA 128
#define NF 512
#define ND 6
#define NC 512
#define NATOMS (NB * NA)   // 32768

typedef __attribute__((ext_vector_type(8))) short frag8;
typedef __attribute__((ext_vector_type(4))) float f32x4;

static __device__ inline unsigned short f2bu(float f) {
    __hip_bfloat16 h = __float2bfloat16(f);
    return *reinterpret_cast<unsigned short*>(&h);
}
static __device__ inline unsigned int pack2(float a, float b) {
    return (unsigned int)f2bu(a) | ((unsigned int)f2bu(b) << 16);
}
static __device__ inline void async16(const void* g, void* l) {
    __builtin_amdgcn_global_load_lds(
        (const __attribute__((address_space(1))) void*)g,
        (__attribute__((address_space(3))) void*)l, 16, 0, 0);
}

// ---------------- kernel T: W[d][f][c] (f32) -> Wt[d][c][f] (bf16) ----------------
// Also zeroes counts[] (runs before bucket_atoms on the stream).
__global__ void transpose_w(const float* __restrict__ W,
                            __hip_bfloat16* __restrict__ Wt,
                            int* __restrict__ counts) {
    if (blockIdx.x == 0 && blockIdx.y == 0 && blockIdx.z == 0 &&
        threadIdx.y == 0 && threadIdx.x < ND)
        counts[threadIdx.x] = 0;
    __shared__ float t[32][33];
    const int d  = blockIdx.z;
    const int c0 = blockIdx.x * 32;
    const int f0 = blockIdx.y * 32;
    #pragma unroll
    for (int r = 0; r < 32; r += 8)
        t[threadIdx.y + r][threadIdx.x] =
            W[((size_t)(d * NF + f0 + threadIdx.y + r)) * NC + c0 + threadIdx.x];
    __syncthreads();
    #pragma unroll
    for (int r = 0; r < 32; r += 8)
        Wt[((size_t)(d * NC + c0 + threadIdx.y + r)) * NF + f0 + threadIdx.x] =
            __float2bfloat16(t[threadIdx.x][threadIdx.y + r]);
}

// ---------------- kernel D: degree bucketing, LDS-aggregated ----------------
__global__ __launch_bounds__(256) void bucket_atoms(
    const int* __restrict__ bonds, int* __restrict__ counts,
    int* __restrict__ bucket) {
    __shared__ int lcnt[ND];
    __shared__ int lbase[ND];
    const int tid = threadIdx.x;
    if (tid < ND) lcnt[tid] = 0;
    __syncthreads();
    int deg[4], loc[4], gg[4];
    #pragma unroll
    for (int i = 0; i < 4; ++i) {
        int g = blockIdx.x * 1024 + i * 256 + tid;
        gg[i] = g;
        int dg = 0;
        #pragma unroll
        for (int j = 0; j < ND; ++j) dg += (bonds[g * ND + j] >= 0);
        deg[i] = dg;
        loc[i] = atomicAdd(&lcnt[dg], 1);      // LDS atomic — cheap
    }
    __syncthreads();
    if (tid < ND) lbase[tid] = atomicAdd(&counts[tid], lcnt[tid]);  // 6 global/block
    __syncthreads();
    #pragma unroll
    for (int i = 0; i < 4; ++i)
        bucket[deg[i] * NATOMS + lbase[deg[i]] + loc[i]] = gg[i];
}

// ---------------- kernel A: neighbor gather/sum (f32) -> summed (bf16) ----------
// XCD-chunked swizzle: each XCD owns 32 contiguous molecules so the ~7x
// per-molecule gather re-reads hit its own L2 (4 MB >> 256 KB molecule).
__global__ __launch_bounds__(256) void sum_neigh(
    const float* __restrict__ atoms, const int* __restrict__ bonds,
    __hip_bfloat16* __restrict__ summed) {
    const int tid  = threadIdx.x;
    const int wave = tid >> 6;
    const int lane = tid & 63;
    const int swz  = (blockIdx.x & 7) * (NATOMS / 4 / 8) + (blockIdx.x >> 3);
    const int g    = swz * 4 + wave;          // atom index [0, 32768)
    const float4* a4 = (const float4*)atoms;  // row = 128 float4

    int   nb[ND];
    float msk[ND];
    #pragma unroll
    for (int j = 0; j < ND; ++j) {
        int n = bonds[g * ND + j];
        msk[j] = (n >= 0) ? 1.0f : 0.0f;
        nb[j]  = (n >= 0) ? n : 0;            // dummy row 0, masked out
    }
    const int rowbase = g & ~(NA - 1);        // (g / NA) * NA

    float4 s0 = a4[(size_t)g * 128 + lane];
    float4 s1 = a4[(size_t)g * 128 + 64 + lane];
    float4 v0[ND], v1[ND];
    #pragma unroll
    for (int j = 0; j < ND; ++j) {
        const size_t base = (size_t)(rowbase + nb[j]) * 128;
        v0[j] = a4[base + lane];
        v1[j] = a4[base + 64 + lane];
    }
    #pragma unroll
    for (int j = 0; j < ND; ++j) {
        s0.x = fmaf(v0[j].x, msk[j], s0.x); s0.y = fmaf(v0[j].y, msk[j], s0.y);
        s0.z = fmaf(v0[j].z, msk[j], s0.z); s0.w = fmaf(v0[j].w, msk[j], s0.w);
        s1.x = fmaf(v1[j].x, msk[j], s1.x); s1.y = fmaf(v1[j].y, msk[j], s1.y);
        s1.z = fmaf(v1[j].z, msk[j], s1.z); s1.w = fmaf(v1[j].w, msk[j], s1.w);
    }

    uint2 o0, o1;
    o0.x = pack2(s0.x, s0.y); o0.y = pack2(s0.z, s0.w);
    o1.x = pack2(s1.x, s1.y); o1.y = pack2(s1.z, s1.w);
    ((uint2*)summed)[(size_t)g * 128 + lane] = o0;
    ((uint2*)summed)[(size_t)g * 128 + 64 + lane] = o1;
}

// ---------------- kernel B: per-degree gathered GEMM ----------------
// BM=BN=128, BK=64. MFMA 16x16x32 bf16; 4 waves, each owns 64x64.
// Counted-vmcnt 2-deep pipeline: tile kt lives in buf kt&1.
//   prologue: stage(tile0)
//   iter kt=1..7: stage(tile kt) ; vmcnt(8) [tile kt-1 done, tile kt in
//                 flight] ; s_barrier ; MFMA(tile kt-1) ; s_barrier
//   epilogue: vmcnt(0) ; s_barrier ; MFMA(tile7)
// LDS swizzle (T2): LDS[row][s] holds global segment s^(row&7); staged by
// pre-swizzling the GLOBAL source segment (gload_lds dest stays linear,
// rule 21); ds_read uses seg ^ (l16&7) -> 2-way max (free).
// Grid decode: L = bx + 24*by; block L lands on XCD L&7; pair p=(q>>2)*8+(L&7)
// gets its 4 n-tiles consecutive on that XCD -> A row-tile L2-resident.
__global__ __launch_bounds__(256, 2) void gemm_deg(
    const __hip_bfloat16* __restrict__ summed, const __hip_bfloat16* __restrict__ Wt,
    const float* __restrict__ bias, const int* __restrict__ counts,
    const int* __restrict__ bucket, float* __restrict__ out) {
    const int L  = blockIdx.x + 24 * blockIdx.y;   // 0..6143
    const int q  = L >> 3;                          // per-XCD sequence
    const int p  = ((q >> 2) << 3) + (L & 7);       // (d,m0) pair, p%8 = XCD
    const int d  = p % ND;
    const int m0 = (p / ND) * 128;
    const int n0 = (q & 3) * 128;                   // 4 n-tiles consecutive per pair
    const int Md = counts[d];
    if (m0 >= Md) return;

    __shared__ __align__(16) __hip_bfloat16 sA[2][128 * 64];  // [row][k], seg-swizzled
    __shared__ __align__(16) __hip_bfloat16 sB[2][128 * 64];  // [n][k]   (Wt rows)
    __shared__ int sRows[128];

    const int tid = threadIdx.x;
    if (tid < 128) {
        int r = m0 + tid;
        sRows[tid] = (r < Md) ? bucket[d * NATOMS + r] : -1;
    }
    __syncthreads();

    const int lane = tid & 63;
    const int w    = tid >> 6;
    const int srow = lane >> 3;     // 0..7 within an 8-row chunk (== row&7)
    const int seg  = lane & 7;      // 16B segment within a 64-elem row

    // per-wave staging: wave w stages rows w*32 + c*8 + srow, c = 0..3
    const char* smB = (const char*)summed;
    const char* wtB = (const char*)Wt + (size_t)(d * NC + n0) * (NF * 2);
    size_t gA[4];
    int    rowc[4];
    #pragma unroll
    for (int c = 0; c < 4; ++c) {
        rowc[c] = w * 32 + c * 8 + srow;
        int qr = sRows[rowc[c]];
        gA[c] = (size_t)((qr < 0) ? 0 : qr) * (NF * 2);   // dummy row 0 (never stored)
    }
    // pre-swizzled global segment: LDS dest seg holds global seg (seg ^ srow)
    const int segswz = seg ^ srow;

    const int quad = lane >> 4, l16 = lane & 15;
    const int xr   = l16 & 7;       // row&7 of every fragment row this lane reads
    const int wy = w >> 1, wx = w & 1;

    f32x4 acc[4][4];
    #pragma unroll
    for (int i = 0; i < 4; ++i)
        #pragma unroll
        for (int j = 0; j < 4; ++j) acc[i][j] = (f32x4)0.0f;

    auto stage = [&](int buf, int kt) {
        const int koff = kt * 128 + segswz * 16;   // byte offset in 1024B row
        #pragma unroll
        for (int c = 0; c < 4; ++c) {
            async16(smB + gA[c] + koff, &sA[buf][(w * 32 + c * 8) * 64]);
            async16(wtB + (size_t)rowc[c] * (NF * 2) + koff, &sB[buf][(w * 32 + c * 8) * 64]);
        }
    };
    auto compute = [&](int buf) {
        #pragma unroll
        for (int ks8 = 0; ks8 < 8; ks8 += 4) {     // logical 16B-seg base: 0 or 4
            frag8 aF[4], bF[4];
            #pragma unroll
            for (int i = 0; i < 4; ++i)
                aF[i] = *(const frag8*)&sA[buf][(wy * 64 + i * 16 + l16) * 64 +
                                                (((ks8 + quad) ^ xr) << 3)];
            #pragma unroll
            for (int j = 0; j < 4; ++j)
                bF[j] = *(const frag8*)&sB[buf][(wx * 64 + j * 16 + l16) * 64 +
                                                (((ks8 + quad) ^ xr) << 3)];
            #pragma unroll
            for (int i = 0; i < 4; ++i)
                #pragma unroll
                for (int j = 0; j < 4; ++j)
                    acc[i][j] = __builtin_amdgcn_mfma_f32_16x16x32_bf16(
                        aF[i], bF[j], acc[i][j], 0, 0, 0);
        }
    };

    stage(0, 0);                                   // tile 0 -> buf 0
    #pragma unroll
    for (int kt = 1; kt < NF / 64; ++kt) {
        stage(kt & 1, kt);                         // tile kt in flight
        asm volatile("s_waitcnt vmcnt(8)" ::: "memory");  // tile kt-1 landed
        __builtin_amdgcn_s_barrier();
        __builtin_amdgcn_s_setprio(1);
        compute((kt - 1) & 1);
        __builtin_amdgcn_s_setprio(0);
        __builtin_amdgcn_s_barrier();              // all waves done reading buf
    }
    asm volatile("s_waitcnt vmcnt(0)" ::: "memory");
    __builtin_amdgcn_s_barrier();
    __builtin_amdgcn_s_setprio(1);
    compute((NF / 64 - 1) & 1);                    // tile 7
    __builtin_amdgcn_s_setprio(0);

    // epilogue: C/D layout col = lane&15, row = quad*4 + reg; output is FLOAT32
    #pragma unroll
    for (int j = 0; j < 4; ++j) {
        const int n = n0 + wx * 64 + j * 16 + l16;
        const float bv = bias[d * NC + n];
        #pragma unroll
        for (int i = 0; i < 4; ++i) {
            #pragma unroll
            for (int r = 0; r < 4; ++r) {
                const int tr = wy * 64 + i * 16 + quad * 4 + r;
                const int g  = sRows[tr];
                if (g >= 0)
                    out[(size_t)g * NC + n] = acc[i][j][r] + bv;
            }
        }
    }
}

extern "C" void kernel_launch(void* const* d_in, const int* in_sizes, int n_in,
                              void* d_out, int out_size, void* d_ws, size_t ws_size,
                              hipStream_t stream) {
    const float* atoms = (const float*)d_in[0];
    const int*   bonds = (const int*)d_in[1];
    const float* W     = (const float*)d_in[2];
    const float* bias  = (const float*)d_in[3];
    float* out = (float*)d_out;

    // workspace layout
    char* ws = (char*)d_ws;
    int* counts = (int*)ws;                                   // 6 ints
    int* bucket = (int*)(ws + 1024);                          // 6*32768 ints = 786432 B
    __hip_bfloat16* Wt     = (__hip_bfloat16*)(ws + 1024 + 786432);            // 3 MB
    __hip_bfloat16* summed = (__hip_bfloat16*)(ws + 1024 + 786432 + 3145728);  // 32 MB

    transpose_w<<<dim3(NC / 32, NF / 32, ND), dim3(32, 8), 0, stream>>>(W, Wt, counts);

    bucket_atoms<<<NATOMS / 1024, 256, 0, stream>>>(bonds, counts, bucket);

    sum_neigh<<<NATOMS / 4, 256, 0, stream>>>(atoms, bonds, summed);

    gemm_deg<<<dim3(24, NATOMS / 128), 256, 0, stream>>>(
        summed, Wt, bias, counts, bucket, out);
}

// Round 3
// 176.768 us; speedup vs baseline: 1.1262x; 1.0856x over previous
//
#include <hip/hip_runtime.h>
#include <hip/hip_bf16.h>

// Problem: B=256, A=128, F=512, D=6, C=512
// out[b,a,:] = (atoms[b,a,:] + sum_j atoms[b,bonds[b,a,j],:]) @ W[deg] + bias[deg]
// deg = count(bonds != -1), in 0..5.
//
// R7: (1) gemm: BK=32, TRIPLE-buffered LDS (49.7 KB -> 3 blocks/CU, 12
//     waves/CU), 2-tile-ahead prefetch, ONE barrier per K-step
//     (wait vmcnt(4) -> s_barrier -> stage(kt+2) -> MFMA(kt)); counted
//     vmcnt never drains to 0 in the loop. Swizzle re-derived for BK=32:
//     slot = seg ^ ((row>>1)&3), pre-swizzled on the global source (rule 21).
//     (2) transpose_w + bucket_atoms + sum_neigh fused into one grid-split
//     `prep` kernel (independent inputs/outputs): 2 fewer launch gaps, and
//     prep becomes visible in rocprof top-5 if it dominates.
//     Kept: XCD-clustered gemm grid decode (FETCH 29.5 MB, verified R5/R6),
//     sum_neigh XCD chunking, T5 setprio around MFMA cluster.

#define NB 256
#define NA 128
#define NF 512
#define ND 6
#define NC 512
#define NATOMS (NB * NA)   // 32768

#define NT_TRANS 1536      // transpose role blocks (16 x 16 x 6)
#define NT_BUCK  32        // bucket role blocks
#define NT_SUM   8192      // sum_neigh role blocks (NATOMS/4)

typedef __attribute__((ext_vector_type(8))) short frag8;
typedef __attribute__((ext_vector_type(4))) float f32x4;

static __device__ inline unsigned short f2bu(float f) {
    __hip_bfloat16 h = __float2bfloat16(f);
    return *reinterpret_cast<unsigned short*>(&h);
}
static __device__ inline unsigned int pack2(float a, float b) {
    return (unsigned int)f2bu(a) | ((unsigned int)f2bu(b) << 16);
}
static __device__ inline void async16(const void* g, void* l) {
    __builtin_amdgcn_global_load_lds(
        (const __attribute__((address_space(1))) void*)g,
        (__attribute__((address_space(3))) void*)l, 16, 0, 0);
}

// ---------------- kernel P: fused prep (transpose_w | bucket | sum_neigh) ----
// Roles are block-level (no divergence inside a block); all three are
// mutually independent so they co-schedule across the GPU in one dispatch.
__global__ __launch_bounds__(256) void prep(
    const float* __restrict__ W, __hip_bfloat16* __restrict__ Wt,
    const int* __restrict__ bonds, int* __restrict__ counts,
    int* __restrict__ bucket,
    const float* __restrict__ atoms, __hip_bfloat16* __restrict__ summed) {
    const int bid = blockIdx.x;
    const int tid = threadIdx.x;
    __shared__ float t[32][33];
    __shared__ int lcnt[ND];
    __shared__ int lbase[ND];

    if (bid < NT_TRANS) {
        // ---- transpose role: W[d][f][c] f32 -> Wt[d][c][f] bf16 ----
        const int tx = tid & 31, ty = tid >> 5;           // 32 x 8
        const int c0 = (bid & 15) * 32;
        const int f0 = ((bid >> 4) & 15) * 32;
        const int d  = bid >> 8;
        #pragma unroll
        for (int r = 0; r < 32; r += 8)
            t[ty + r][tx] =
                W[((size_t)(d * NF + f0 + ty + r)) * NC + c0 + tx];
        __syncthreads();
        #pragma unroll
        for (int r = 0; r < 32; r += 8)
            Wt[((size_t)(d * NC + c0 + ty + r)) * NF + f0 + tx] =
                __float2bfloat16(t[tx][ty + r]);
        return;
    }
    if (bid < NT_TRANS + NT_BUCK) {
        // ---- bucket role: degree bucketing, LDS-aggregated ----
        const int b = bid - NT_TRANS;
        if (tid < ND) lcnt[tid] = 0;
        __syncthreads();
        int deg[4], loc[4], gg[4];
        #pragma unroll
        for (int i = 0; i < 4; ++i) {
            int g = b * 1024 + i * 256 + tid;
            gg[i] = g;
            int dg = 0;
            #pragma unroll
            for (int j = 0; j < ND; ++j) dg += (bonds[g * ND + j] >= 0);
            deg[i] = dg;
            loc[i] = atomicAdd(&lcnt[dg], 1);
        }
        __syncthreads();
        if (tid < ND) lbase[tid] = atomicAdd(&counts[tid], lcnt[tid]);
        __syncthreads();
        #pragma unroll
        for (int i = 0; i < 4; ++i)
            bucket[deg[i] * NATOMS + lbase[deg[i]] + loc[i]] = gg[i];
        return;
    }
    // ---- sum_neigh role: gather/sum neighbours f32 -> bf16 ----
    // XCD-chunked: each XCD owns 32 contiguous molecules (2 MB working set
    // resident per XCD < 4 MB L2) so the ~7x gather re-reads L2-hit.
    const int sbid = bid - (NT_TRANS + NT_BUCK);
    const int wave = tid >> 6;
    const int lane = tid & 63;
    const int swz  = (sbid & 7) * (NT_SUM / 8) + (sbid >> 3);
    const int g    = swz * 4 + wave;          // atom index [0, 32768)
    const float4* a4 = (const float4*)atoms;  // row = 128 float4

    int   nb[ND];
    float msk[ND];
    #pragma unroll
    for (int j = 0; j < ND; ++j) {
        int n = bonds[g * ND + j];
        msk[j] = (n >= 0) ? 1.0f : 0.0f;
        nb[j]  = (n >= 0) ? n : 0;            // dummy row 0, masked out
    }
    const int rowbase = g & ~(NA - 1);        // (g / NA) * NA

    float4 s0 = a4[(size_t)g * 128 + lane];
    float4 s1 = a4[(size_t)g * 128 + 64 + lane];
    float4 v0[ND], v1[ND];
    #pragma unroll
    for (int j = 0; j < ND; ++j) {
        const size_t base = (size_t)(rowbase + nb[j]) * 128;
        v0[j] = a4[base + lane];
        v1[j] = a4[base + 64 + lane];
    }
    #pragma unroll
    for (int j = 0; j < ND; ++j) {
        s0.x = fmaf(v0[j].x, msk[j], s0.x); s0.y = fmaf(v0[j].y, msk[j], s0.y);
        s0.z = fmaf(v0[j].z, msk[j], s0.z); s0.w = fmaf(v0[j].w, msk[j], s0.w);
        s1.x = fmaf(v1[j].x, msk[j], s1.x); s1.y = fmaf(v1[j].y, msk[j], s1.y);
        s1.z = fmaf(v1[j].z, msk[j], s1.z); s1.w = fmaf(v1[j].w, msk[j], s1.w);
    }

    uint2 o0, o1;
    o0.x = pack2(s0.x, s0.y); o0.y = pack2(s0.z, s0.w);
    o1.x = pack2(s1.x, s1.y); o1.y = pack2(s1.z, s1.w);
    ((uint2*)summed)[(size_t)g * 128 + lane] = o0;
    ((uint2*)summed)[(size_t)g * 128 + 64 + lane] = o1;
}

// ---------------- kernel B: per-degree gathered GEMM ----------------
// BM=BN=128, BK=32. MFMA 16x16x32 bf16; 4 waves, each owns 64x64.
// Triple-buffered, 2-tile-ahead counted-vmcnt pipeline, ONE barrier/K-step:
//   prologue: stage(t0->buf0), stage(t1->buf1)
//   iter kt=0..15:
//     s_waitcnt vmcnt(4)   [tile kt landed; kt+1 still in flight]  (0 at kt=15)
//     s_barrier            [all waves: tile kt visible, buf (kt+2)%3 free]
//     stage(tile kt+2 -> buf (kt+2)%3)      [if kt+2 < 16]
//     setprio(1); 16x MFMA on buf kt%3; setprio(0)
// Hazard-free: stage target buf (kt+2)%3 != compute buf kt%3 != in-flight
// (kt+1)%3, and the barrier precedes the stage so no wave still reads it.
// LDS swizzle (T2, BK=32): LDS[row][slot] holds global seg slot^((row>>1)&3)
// -> ds_read_b128 lands 2-way max (free). Staged by pre-swizzling the GLOBAL
// source segment; gload_lds dest stays linear (rule 21).
// Grid decode: L = bx+24*by; XCD L&7; pair p's 4 n-tiles consecutive on one
// XCD -> A row-tile L2-resident (FETCH 29.5 MB, verified).
__global__ __launch_bounds__(256, 3) void gemm_deg(
    const __hip_bfloat16* __restrict__ summed, const __hip_bfloat16* __restrict__ Wt,
    const float* __restrict__ bias, const int* __restrict__ counts,
    const int* __restrict__ bucket, float* __restrict__ out) {
    const int L  = blockIdx.x + 24 * blockIdx.y;   // 0..6143
    const int q  = L >> 3;                          // per-XCD sequence
    const int p  = ((q >> 2) << 3) + (L & 7);       // (d,m0) pair, p%8 = XCD
    const int d  = p % ND;
    const int m0 = (p / ND) * 128;
    const int n0 = (q & 3) * 128;                   // 4 n-tiles consecutive per pair
    const int Md = counts[d];
    if (m0 >= Md) return;

    __shared__ __align__(16) __hip_bfloat16 sA[3][128 * 32];  // [row][k] swizzled
    __shared__ __align__(16) __hip_bfloat16 sB[3][128 * 32];  // [n][k]  (Wt rows)
    __shared__ int sRows[128];

    const int tid = threadIdx.x;
    if (tid < 128) {
        int r = m0 + tid;
        sRows[tid] = (r < Md) ? bucket[d * NATOMS + r] : -1;
    }
    __syncthreads();

    const int lane = tid & 63;
    const int w    = tid >> 6;

    // staging coords: thread covers LDS rows {srow2, 64+srow2}, 16B slot `slot`
    const int srow2 = tid >> 2;                    // 0..63
    const int slot  = tid & 3;
    const int gs    = slot ^ ((srow2 >> 1) & 3);   // pre-swizzled global segment

    const char* smB = (const char*)summed;
    const char* wtB = (const char*)Wt + (size_t)(d * NC + n0) * (NF * 2);
    size_t gA[2];
    #pragma unroll
    for (int c = 0; c < 2; ++c) {
        int qr = sRows[c * 64 + srow2];
        gA[c] = (size_t)((qr < 0) ? 0 : qr) * (NF * 2);   // dummy row 0
    }

    const int quad = lane >> 4, l16 = lane & 15;
    const int xr2  = (l16 >> 1) & 3;               // row-derived read swizzle
    const int wy = w >> 1, wx = w & 1;

    f32x4 acc[4][4];
    #pragma unroll
    for (int i = 0; i < 4; ++i)
        #pragma unroll
        for (int j = 0; j < 4; ++j) acc[i][j] = (f32x4)0.0f;

    // per-wave-uniform LDS bases (HW adds lane*16): wave w, chunk c covers
    // rows c*64 + w*16 .. +15  ->  byte base = c*4096 + w*1024
    auto stage = [&](int buf, int kt) {
        const int koff = kt * 64 + gs * 16;        // byte offset in 1024B row
        #pragma unroll
        for (int c = 0; c < 2; ++c) {
            async16(smB + gA[c] + koff, &sA[buf][c * 2048 + w * 512]);
            async16(wtB + (size_t)(c * 64 + srow2) * (NF * 2) + koff,
                    &sB[buf][c * 2048 + w * 512]);
        }
    };
    auto compute = [&](int buf) {
        frag8 aF[4], bF[4];
        #pragma unroll
        for (int i = 0; i < 4; ++i)
            aF[i] = *(const frag8*)&sA[buf][(wy * 64 + i * 16 + l16) * 32 +
                                            ((quad ^ xr2) << 3)];
        #pragma unroll
        for (int j = 0; j < 4; ++j)
            bF[j] = *(const frag8*)&sB[buf][(wx * 64 + j * 16 + l16) * 32 +
                                            ((quad ^ xr2) << 3)];
        #pragma unroll
        for (int i = 0; i < 4; ++i)
            #pragma unroll
            for (int j = 0; j < 4; ++j)
                acc[i][j] = __builtin_amdgcn_mfma_f32_16x16x32_bf16(
                    aF[i], bF[j], acc[i][j], 0, 0, 0);
    };

    stage(0, 0);                                   // tile 0 -> buf 0
    stage(1, 1);                                   // tile 1 -> buf 1
    #pragma unroll
    for (int kt = 0; kt < NF / 32; ++kt) {
        if (kt < NF / 32 - 1)
            asm volatile("s_waitcnt vmcnt(4)" ::: "memory");  // tile kt landed
        else
            asm volatile("s_waitcnt vmcnt(0)" ::: "memory");
        __builtin_amdgcn_sched_barrier(0);
        __builtin_amdgcn_s_barrier();              // tile kt visible to all;
                                                   // buf (kt+2)%3 free
        if (kt + 2 < NF / 32) stage((kt + 2) % 3, kt + 2);
        __builtin_amdgcn_s_setprio(1);
        compute(kt % 3);
        __builtin_amdgcn_s_setprio(0);
    }

    // epilogue: C/D layout col = lane&15, row = quad*4 + reg; output FLOAT32
    #pragma unroll
    for (int j = 0; j < 4; ++j) {
        const int n = n0 + wx * 64 + j * 16 + l16;
        const float bv = bias[d * NC + n];
        #pragma unroll
        for (int i = 0; i < 4; ++i) {
            #pragma unroll
            for (int r = 0; r < 4; ++r) {
                const int tr = wy * 64 + i * 16 + quad * 4 + r;
                const int g  = sRows[tr];
                if (g >= 0)
                    out[(size_t)g * NC + n] = acc[i][j][r] + bv;
            }
        }
    }
}

extern "C" void kernel_launch(void* const* d_in, const int* in_sizes, int n_in,
                              void* d_out, int out_size, void* d_ws, size_t ws_size,
                              hipStream_t stream) {
    const float* atoms = (const float*)d_in[0];
    const int*   bonds = (const int*)d_in[1];
    const float* W     = (const float*)d_in[2];
    const float* bias  = (const float*)d_in[3];
    float* out = (float*)d_out;

    // workspace layout
    char* ws = (char*)d_ws;
    int* counts = (int*)ws;                                   // 6 ints
    int* bucket = (int*)(ws + 1024);                          // 6*32768 ints = 786432 B
    __hip_bfloat16* Wt     = (__hip_bfloat16*)(ws + 1024 + 786432);            // 3 MB
    __hip_bfloat16* summed = (__hip_bfloat16*)(ws + 1024 + 786432 + 3145728);  // 32 MB

    hipMemsetAsync(counts, 0, 1024, stream);

    prep<<<NT_TRANS + NT_BUCK + NT_SUM, 256, 0, stream>>>(
        W, Wt, bonds, counts, bucket, atoms, summed);

    gemm_deg<<<dim3(24, NATOMS / 128), 256, 0, stream>>>(
        summed, Wt, bias, counts, bucket, out);
}